// Round 2
// baseline (453.306 us; speedup 1.0000x reference)
//
#include <hip/hip_runtime.h>
#include <math.h>

#define N_NODES 50000
#define N_EDGES 800000
#define TOT (N_NODES + N_EDGES)   // edges + self loops
#define F_IN 128
#define C1 100
#define C2 4
#define NEG 0.2f

__device__ __forceinline__ float leaky(float v) { return v > 0.f ? v : NEG * v; }

// ---------- CSR build ----------
__global__ __launch_bounds__(256) void k_count(const int* __restrict__ ei, int* __restrict__ counts) {
    int i = blockIdx.x * 256 + threadIdx.x;
    if (i >= TOT) return;
    int d = (i < N_EDGES) ? ei[N_EDGES + i] : (i - N_EDGES);
    if ((unsigned)d < N_NODES) atomicAdd(&counts[d], 1);
}

__global__ __launch_bounds__(256) void k_scan1(const int* __restrict__ counts, int* __restrict__ incl,
                                               int* __restrict__ bsums) {
    __shared__ int s[256];
    int t = threadIdx.x;
    int i = blockIdx.x * 256 + t;
    int v = (i < N_NODES) ? counts[i] : 0;
    s[t] = v;
    __syncthreads();
    for (int off = 1; off < 256; off <<= 1) {
        int u = (t >= off) ? s[t - off] : 0;
        __syncthreads();
        s[t] += u;
        __syncthreads();
    }
    if (i < N_NODES) incl[i] = s[t];
    if (t == 255) bsums[blockIdx.x] = s[255];
}

__global__ __launch_bounds__(256) void k_scan2(const int* __restrict__ bsums, int* __restrict__ boff, int nb) {
    __shared__ int s[256];
    int t = threadIdx.x;
    int v = (t < nb) ? bsums[t] : 0;
    s[t] = v;
    __syncthreads();
    for (int off = 1; off < 256; off <<= 1) {
        int u = (t >= off) ? s[t - off] : 0;
        __syncthreads();
        s[t] += u;
        __syncthreads();
    }
    if (t < nb) boff[t] = s[t] - v;  // exclusive
}

__global__ __launch_bounds__(256) void k_scan3(const int* __restrict__ counts, const int* __restrict__ incl,
                                               const int* __restrict__ boff, int* __restrict__ offsets,
                                               int* __restrict__ cur) {
    int i = blockIdx.x * 256 + threadIdx.x;
    if (i >= N_NODES) return;
    int excl = boff[i >> 8] + incl[i] - counts[i];
    offsets[i] = excl;
    cur[i] = excl;
    if (i == N_NODES - 1) offsets[N_NODES] = excl + counts[i];
}

__global__ __launch_bounds__(256) void k_scatter(const int* __restrict__ ei, int* __restrict__ cur,
                                                 int* __restrict__ csr_src) {
    int i = blockIdx.x * 256 + threadIdx.x;
    if (i >= TOT) return;
    int s, d;
    if (i < N_EDGES) { s = ei[i]; d = ei[N_EDGES + i]; }
    else             { s = i - N_EDGES; d = s; }
    if ((unsigned)d >= N_NODES) return;
    int slot = atomicAdd(&cur[d], 1);
    csr_src[slot] = s;
}

// ---------- Layer 1 GEMM: h1 = x @ W1  (50000x128 @ 128x100) ----------
__global__ __launch_bounds__(256) void k_gemm1(const float* __restrict__ x, const float* __restrict__ W1,
                                               float* __restrict__ h1) {
    __shared__ float sW[32 * 100];  // K-chunk of W1
    __shared__ float sX[32 * 32];   // 32 nodes x 32 k
    int tid = threadIdx.x;
    int node0 = blockIdx.x * 32;
    int ni = tid >> 5, ci = tid & 31;
    float acc[4][4] = {};
    for (int k0 = 0; k0 < F_IN; k0 += 32) {
        __syncthreads();
        for (int f = tid; f < 3200; f += 256) sW[f] = W1[k0 * C1 + f];  // contiguous chunk
        {
            int nl = tid >> 3;
            int kk4 = (tid & 7) * 4;
            int n = node0 + nl;
            float4 v = make_float4(0.f, 0.f, 0.f, 0.f);
            if (n < N_NODES) v = *(const float4*)(x + (long)n * F_IN + k0 + kk4);
            *(float4*)(&sX[nl * 32 + kk4]) = v;
        }
        __syncthreads();
        for (int kk = 0; kk < 32; ++kk) {
            float xr[4];
#pragma unroll
            for (int r = 0; r < 4; ++r) xr[r] = sX[(ni + 8 * r) * 32 + kk];
            float w0 = sW[kk * C1 + ci];
            float w1 = sW[kk * C1 + ci + 32];
            float w2 = sW[kk * C1 + ci + 64];
            float w3 = (ci < 4) ? sW[kk * C1 + ci + 96] : 0.f;
#pragma unroll
            for (int r = 0; r < 4; ++r) {
                acc[r][0] += xr[r] * w0;
                acc[r][1] += xr[r] * w1;
                acc[r][2] += xr[r] * w2;
                acc[r][3] += xr[r] * w3;
            }
        }
    }
#pragma unroll
    for (int r = 0; r < 4; ++r) {
        int n = node0 + ni + 8 * r;
        if (n >= N_NODES) continue;
#pragma unroll
        for (int q = 0; q < 4; ++q) {
            int c = ci + 32 * q;
            if (c < C1) h1[(long)n * C1 + c] = acc[r][q];
        }
    }
}

// ---------- Layer 1 attention dots ----------
__global__ __launch_bounds__(256) void k_dots1(const float* __restrict__ h1, const float* __restrict__ as,
                                               const float* __restrict__ adv, float* __restrict__ a_src,
                                               float* __restrict__ a_dst) {
    int wave = threadIdx.x >> 6, lane = threadIdx.x & 63;
    int n = blockIdx.x * 4 + wave;
    if (n >= N_NODES) return;
    int k = lane * 2;
    float ps = 0.f, pd = 0.f;
    if (k < C1) {
        float2 h = *(const float2*)(h1 + (long)n * C1 + k);
        ps = h.x * as[k] + h.y * as[k + 1];
        pd = h.x * adv[k] + h.y * adv[k + 1];
    }
    for (int off = 32; off; off >>= 1) {
        ps += __shfl_xor(ps, off);
        pd += __shfl_xor(pd, off);
    }
    if (lane == 0) { a_src[n] = ps; a_dst[n] = pd; }
}

// ---------- Layer 1 segment softmax + aggregate + bias + ReLU ----------
__global__ __launch_bounds__(128) void k_agg1(const float* __restrict__ h1, const float* __restrict__ a_src,
                                              const float* __restrict__ a_dst, const int* __restrict__ offsets,
                                              const int* __restrict__ csr_src, const float* __restrict__ b1,
                                              float* __restrict__ h1r) {
    int d = blockIdx.x;
    int beg = offsets[d], end = offsets[d + 1];
    float ad = a_dst[d];
    __shared__ float s_m, s_l;
    int tid = threadIdx.x;
    if (tid < 64) {
        float m = -1e30f;
        for (int j = beg + tid; j < end; j += 64)
            m = fmaxf(m, leaky(a_src[csr_src[j]] + ad));
        for (int off = 32; off; off >>= 1) m = fmaxf(m, __shfl_xor(m, off));
        float l = 0.f;
        for (int j = beg + tid; j < end; j += 64)
            l += __expf(leaky(a_src[csr_src[j]] + ad) - m);
        for (int off = 32; off; off >>= 1) l += __shfl_xor(l, off);
        if (tid == 0) { s_m = m; s_l = l; }
    }
    __syncthreads();
    float m = s_m, invl = 1.f / s_l;
    int c = tid;
    float acc = 0.f;
    for (int j = beg; j < end; ++j) {
        int s = csr_src[j];
        float w = __expf(leaky(a_src[s] + ad) - m);
        if (c < C1) acc += w * h1[(long)s * C1 + c];
    }
    if (c < C1) h1r[(long)d * C1 + c] = fmaxf(acc * invl + b1[c], 0.f);
}

// ---------- Layer 2 GEMM (100->4) + attention dots, wave per node ----------
__global__ __launch_bounds__(256) void k_h2(const float* __restrict__ h1r, const float* __restrict__ W2,
                                            const float* __restrict__ as2, const float* __restrict__ ad2,
                                            float* __restrict__ h2, float* __restrict__ a_src2,
                                            float* __restrict__ a_dst2) {
    __shared__ float sW[C1 * C2];
    int tid = threadIdx.x;
    for (int f = tid; f < C1 * C2; f += 256) sW[f] = W2[f];   // FIX: 400 > 256, must stride
    __syncthreads();
    int wave = tid >> 6, lane = tid & 63;
    int n = blockIdx.x * 4 + wave;
    if (n >= N_NODES) return;
    float p0 = 0.f, p1 = 0.f, p2 = 0.f, p3 = 0.f;
    for (int k = lane; k < C1; k += 64) {
        float hv = h1r[(long)n * C1 + k];
        p0 += hv * sW[k * 4 + 0];
        p1 += hv * sW[k * 4 + 1];
        p2 += hv * sW[k * 4 + 2];
        p3 += hv * sW[k * 4 + 3];
    }
    for (int off = 32; off; off >>= 1) {
        p0 += __shfl_xor(p0, off);
        p1 += __shfl_xor(p1, off);
        p2 += __shfl_xor(p2, off);
        p3 += __shfl_xor(p3, off);
    }
    if (lane == 0) {
        *(float4*)(h2 + (long)n * 4) = make_float4(p0, p1, p2, p3);
        a_src2[n] = p0 * as2[0] + p1 * as2[1] + p2 * as2[2] + p3 * as2[3];
        a_dst2[n] = p0 * ad2[0] + p1 * ad2[1] + p2 * ad2[2] + p3 * ad2[3];
    }
}

// ---------- Layer 2 softmax aggregate + bias + log_softmax ----------
__global__ __launch_bounds__(256) void k_agg2(const float* __restrict__ h2, const float* __restrict__ a_src,
                                              const float* __restrict__ a_dst, const int* __restrict__ offsets,
                                              const int* __restrict__ csr_src, const float* __restrict__ b2,
                                              float* __restrict__ out) {
    int wave = threadIdx.x >> 6, lane = threadIdx.x & 63;
    int d = blockIdx.x * 4 + wave;
    if (d >= N_NODES) return;
    int beg = offsets[d], end = offsets[d + 1];
    float ad = a_dst[d];
    float m = -1e30f;
    for (int j = beg + lane; j < end; j += 64)
        m = fmaxf(m, leaky(a_src[csr_src[j]] + ad));
    for (int off = 32; off; off >>= 1) m = fmaxf(m, __shfl_xor(m, off));
    float l = 0.f, a0 = 0.f, a1 = 0.f, a2 = 0.f, a3 = 0.f;
    for (int j = beg + lane; j < end; j += 64) {
        int s = csr_src[j];
        float w = __expf(leaky(a_src[s] + ad) - m);
        l += w;
        float4 hv = *(const float4*)(h2 + (long)s * 4);
        a0 += w * hv.x; a1 += w * hv.y; a2 += w * hv.z; a3 += w * hv.w;
    }
    for (int off = 32; off; off >>= 1) {
        l += __shfl_xor(l, off);
        a0 += __shfl_xor(a0, off);
        a1 += __shfl_xor(a1, off);
        a2 += __shfl_xor(a2, off);
        a3 += __shfl_xor(a3, off);
    }
    if (lane == 0) {
        float invl = 1.f / l;
        float v0 = a0 * invl + b2[0];
        float v1 = a1 * invl + b2[1];
        float v2 = a2 * invl + b2[2];
        float v3 = a3 * invl + b2[3];
        float mm = fmaxf(fmaxf(v0, v1), fmaxf(v2, v3));
        float ls = logf(__expf(v0 - mm) + __expf(v1 - mm) + __expf(v2 - mm) + __expf(v3 - mm)) + mm;
        *(float4*)(out + (long)d * 4) = make_float4(v0 - ls, v1 - ls, v2 - ls, v3 - ls);
    }
}

extern "C" void kernel_launch(void* const* d_in, const int* in_sizes, int n_in,
                              void* d_out, int out_size, void* d_ws, size_t ws_size,
                              hipStream_t stream) {
    const float* x   = (const float*)d_in[0];
    const int*   ei  = (const int*)d_in[1];   // (2, E) int32 row-major
    const float* W1  = (const float*)d_in[2];
    const float* as1 = (const float*)d_in[3];
    const float* ad1 = (const float*)d_in[4];
    const float* b1  = (const float*)d_in[5];
    const float* W2  = (const float*)d_in[6];
    const float* as2 = (const float*)d_in[7];
    const float* ad2 = (const float*)d_in[8];
    const float* b2  = (const float*)d_in[9];
    float* out = (float*)d_out;

    char* w = (char*)d_ws;
    float* h1      = (float*)(w + 0);           // 20,000,000 B
    float* h1r     = (float*)(w + 20000000);    // 20,000,000 B
    float* a_src1  = (float*)(w + 40000000);    // 200,000 B
    float* a_dst1  = (float*)(w + 40200000);
    float* h2      = (float*)(w + 40400000);    // 800,000 B
    float* a_src2  = (float*)(w + 41200000);
    float* a_dst2  = (float*)(w + 41400000);
    int*   counts  = (int*)(w + 41600000);
    int*   incl    = (int*)(w + 41800000);
    int*   offsets = (int*)(w + 42000000);      // N+1 ints
    int*   cur     = (int*)(w + 42200016);
    int*   csr_src = (int*)(w + 42400016);      // 3,400,000 B
    int*   bsums   = (int*)(w + 45800016);
    int*   boff    = (int*)(w + 45800816);

    const int NB_SCAN = (N_NODES + 255) / 256;  // 196
    const int NB_EDGE = (TOT + 255) / 256;      // 3321

    hipMemsetAsync(counts, 0, N_NODES * sizeof(int), stream);
    k_count<<<NB_EDGE, 256, 0, stream>>>(ei, counts);
    k_scan1<<<NB_SCAN, 256, 0, stream>>>(counts, incl, bsums);
    k_scan2<<<1, 256, 0, stream>>>(bsums, boff, NB_SCAN);
    k_scan3<<<NB_SCAN, 256, 0, stream>>>(counts, incl, boff, offsets, cur);
    k_scatter<<<NB_EDGE, 256, 0, stream>>>(ei, cur, csr_src);

    k_gemm1<<<(N_NODES + 31) / 32, 256, 0, stream>>>(x, W1, h1);
    k_dots1<<<(N_NODES + 3) / 4, 256, 0, stream>>>(h1, as1, ad1, a_src1, a_dst1);
    k_agg1<<<N_NODES, 128, 0, stream>>>(h1, a_src1, a_dst1, offsets, csr_src, b1, h1r);

    k_h2<<<(N_NODES + 3) / 4, 256, 0, stream>>>(h1r, W2, as2, ad2, h2, a_src2, a_dst2);
    k_agg2<<<(N_NODES + 3) / 4, 256, 0, stream>>>(h2, a_src2, a_dst2, offsets, csr_src, b2, out);
}